// Round 1
// baseline (129.034 us; speedup 1.0000x reference)
//
#include <hip/hip_runtime.h>

#define B_ 16
#define A_ 3
#define G_ 76
#define GG_ (G_*G_)            // 5776
#define NC_ 80
#define C_ 85
#define CH_ 255
#define STRIDE_ 8.0f
#define NCELL (B_*A_*GG_)      // 277248
#define OUTN ((size_t)NCELL*C_) // 23566080
#define PAD 77

__device__ __forceinline__ float sigf(float v){ return 1.0f/(1.0f + __expf(-v)); }
__device__ __forceinline__ float clog_(float p){ return fmaxf(__logf(p), -100.0f); }
__device__ __forceinline__ float bcef(float p, float t){ return -(t*clog_(p) + (1.0f-t)*clog_(1.0f-p)); }

// ---------------- mask dtype detection ----------------
// masks are jnp bool; harness may give int32 {0,1}, float32 {0,1.0f}, or raw bytes.
// Scan first NCELL/4 words (safe for all three layouts): classify.
__global__ __launch_bounds__(256) void detect_kernel(const unsigned int* __restrict__ m,
                                                     unsigned int* __restrict__ flags){
    unsigned idx = blockIdx.x*256u + threadIdx.x;
    unsigned v = (idx < (NCELL/4)) ? m[idx] : 0u;
    int n01 = (v > 1u);                                   // not an int32 0/1
    int nfl = (v != 0u) && (v != 0x3F800000u);            // not a float32 0/1.0
    if (__any(n01) && (threadIdx.x & 63) == 0) atomicOr(&flags[0], 1u);
    if (__any(nfl) && (threadIdx.x & 63) == 0) atomicOr(&flags[1], 1u);
}

// ---------------- output tensor: transpose + transform ----------------
// block = one (b, a, row i); LDS tile 85 x 76 (padded 77)
__global__ __launch_bounds__(256) void out_kernel(const float* __restrict__ x,
                                                  float* __restrict__ out){
    __shared__ float tile[C_*PAD];
    int blk = blockIdx.x;
    int i  = blk % G_;
    int ba = blk / G_;          // b*A + a
    int a  = ba % A_;
    const float* src = x + ((size_t)(ba*C_ + (ba/A_)*(CH_-A_*C_) ))*GG_ + i*G_;
    // note: b*CH_ + a*C_ == ba*C_ + b*(CH_-A_*C_) ; CH_==A_*C_ so second term is 0.
    for (int idx = threadIdx.x; idx < C_*G_; idx += 256){
        int k = idx / G_;
        int j = idx - k*G_;
        tile[k*PAD + j] = src[(size_t)k*GG_ + j];
    }
    __syncthreads();
    float aw = (a==0)?1.5f:((a==1)?2.375f:5.0f);
    float ah = (a==0)?2.0f:((a==1)?4.5f:3.5f);
    float* dst = out + ((size_t)(ba*GG_ + i*G_))*C_;
    for (int idx = threadIdx.x; idx < G_*C_; idx += 256){
        int m = idx / C_;
        int k = idx - m*C_;
        float v = tile[k*PAD + m];
        float r;
        if (k >= 4)       r = sigf(v);
        else if (k == 0)  r = (sigf(v) + (float)m) * STRIDE_;
        else if (k == 1)  r = (sigf(v) + (float)i) * STRIDE_;
        else if (k == 2)  r = __expf(v) * (aw * STRIDE_);
        else              r = __expf(v) * (ah * STRIDE_);
        dst[idx] = r;
    }
}

// ---------------- loss: one thread per cell ----------------
__global__ __launch_bounds__(256) void loss_kernel(
        const float* __restrict__ x, const float* __restrict__ iou,
        const void* __restrict__ om, const void* __restrict__ nm,
        const float* __restrict__ tw, const float* __restrict__ th,
        const float* __restrict__ tcls, const float* __restrict__ tconf,
        const float* __restrict__ tbox, const unsigned int* __restrict__ flags,
        float* __restrict__ partials){
    int n = blockIdx.x*256 + threadIdx.x;   // grid sized exactly
    int mode = (flags[0]==0u) ? 0 : ((flags[1]==0u) ? 1 : 2);
    bool obj, noobj;
    if (mode == 0){
        obj   = ((const int*)om)[n] != 0;
        noobj = ((const int*)nm)[n] != 0;
    } else if (mode == 1){
        obj   = ((const float*)om)[n] != 0.0f;
        noobj = ((const float*)nm)[n] != 0.0f;
    } else {
        obj   = ((const unsigned char*)om)[n] != 0;
        noobj = ((const unsigned char*)nm)[n] != 0;
    }

    float s_ciou=0.f, s_co=0.f, s_cn=0.f, s_cls=0.f;
    int c_o=0, c_n=0;
    if (obj || noobj){
        int bn  = n / (A_*GG_);
        int rem = n - bn*(A_*GG_);
        int an  = rem / GG_;
        int ij  = rem - an*GG_;
        int in_ = ij / G_;
        int jn  = ij - in_*G_;
        const float* xc = x + ((size_t)(bn*CH_ + an*C_))*GG_ + ij;
        float pconf = sigf(xc[4*GG_]);
        float bc = bcef(pconf, tconf[n]);
        if (noobj){ s_cn = bc; c_n = 1; }
        if (obj){
            s_co = bc; c_o = 1;
            float aw = (an==0)?1.5f:((an==1)?2.375f:5.0f);
            float ah = (an==0)?2.0f:((an==1)?4.5f:3.5f);
            float pxv = sigf(xc[0]);
            float pyv = sigf(xc[GG_]);
            float pwv = xc[2*GG_];
            float phv = xc[3*GG_];
            float bx = pxv + (float)jn;
            float by = pyv + (float)in_;
            float bw = __expf(pwv)*aw;
            float bh = __expf(phv)*ah;
            float txc = tbox[(size_t)n*4+0], tyc = tbox[(size_t)n*4+1];
            float twd = tbox[(size_t)n*4+2], tht = tbox[(size_t)n*4+3];
            float tx1 = txc - twd*0.5f, ty1 = tyc - tht*0.5f;
            float tx2 = txc + twd*0.5f, ty2 = tyc + tht*0.5f;
            float px1 = bx - bw*0.5f,  py1 = by - bh*0.5f;
            float px2 = bx + bw*0.5f,  py2 = by + bh*0.5f;
            float xc1 = fminf(px1, tx1), yc1 = fminf(py1, ty1);
            float xc2 = fmaxf(px2, tx2), yc2 = fmaxf(py2, ty2);
            float cc = (xc2-xc1)*(xc2-xc1) + (yc2-yc1)*(yc2-yc1) + 1e-7f;
            float dd = (txc-bx)*(txc-bx) + (tyc-by)*(tyc-by);
            float rdiou = dd/cc;
            float dat = atanf(tw[n]/th[n]) - atanf(pwv/phv);
            float vv = 0.40528473456935108577f * dat*dat;   // 4/pi^2
            float Si = 1.0f - iou[n];
            float alpha = vv/(Si+vv);
            s_ciou = 1.0f - iou[n] + rdiou + alpha*vv;
            const float* tcl = tcls + (size_t)n*NC_;
            #pragma unroll 4
            for (int c=0;c<NC_;c++){
                float p = sigf(xc[(size_t)(5+c)*GG_]);
                s_cls += bcef(p, tcl[c]);
            }
        }
    }
    // deterministic block reduction
    float vals[6] = {s_ciou, s_co, s_cn, s_cls, (float)c_o, (float)c_n};
    #pragma unroll
    for (int q=0;q<6;q++){
        float v = vals[q];
        for (int o=32;o>0;o>>=1) v += __shfl_down(v, o, 64);
        vals[q] = v;
    }
    __shared__ float sm[6][4];
    int lane = threadIdx.x & 63, wid = threadIdx.x >> 6;
    if (lane == 0){
        #pragma unroll
        for (int q=0;q<6;q++) sm[q][wid] = vals[q];
    }
    __syncthreads();
    if (threadIdx.x == 0){
        #pragma unroll
        for (int q=0;q<6;q++)
            partials[blockIdx.x*6+q] = sm[q][0]+sm[q][1]+sm[q][2]+sm[q][3];
    }
}

// ---------------- final reduction ----------------
__global__ __launch_bounds__(256) void final_kernel(const float* __restrict__ partials,
                                                    float* __restrict__ out_loss){
    double acc[6] = {0,0,0,0,0,0};
    for (int idx = threadIdx.x; idx < NCELL/256; idx += 256){
        #pragma unroll
        for (int q=0;q<6;q++) acc[q] += (double)partials[idx*6+q];
    }
    #pragma unroll
    for (int q=0;q<6;q++){
        double v = acc[q];
        for (int o=32;o>0;o>>=1) v += __shfl_down(v, o, 64);
        acc[q] = v;
    }
    __shared__ double sm[6][4];
    int lane = threadIdx.x & 63, wid = threadIdx.x >> 6;
    if (lane == 0){
        #pragma unroll
        for (int q=0;q<6;q++) sm[q][wid] = acc[q];
    }
    __syncthreads();
    if (threadIdx.x == 0){
        double s[6];
        #pragma unroll
        for (int q=0;q<6;q++) s[q] = sm[q][0]+sm[q][1]+sm[q][2]+sm[q][3];
        double cnt_o = fmax(s[4], 1.0);
        double cnt_n = fmax(s[5], 1.0);
        double total = s[0]/(double)B_            // CIoU / B
                     + s[1]/cnt_o                 // obj conf
                     + 100.0*s[2]/cnt_n           // noobj conf
                     + s[3]/(cnt_o*(double)NC_);  // cls
        *out_loss = (float)total;
    }
}

extern "C" void kernel_launch(void* const* d_in, const int* in_sizes, int n_in,
                              void* d_out, int out_size, void* d_ws, size_t ws_size,
                              hipStream_t stream){
    const float* x     = (const float*)d_in[0];
    const float* iou   = (const float*)d_in[1];
    const void*  om    = d_in[2];
    const void*  nm    = d_in[3];
    const float* tw    = (const float*)d_in[4];
    const float* th    = (const float*)d_in[5];
    const float* tcls  = (const float*)d_in[6];
    const float* tconf = (const float*)d_in[7];
    const float* tbox  = (const float*)d_in[8];
    float* out = (float*)d_out;

    unsigned int* flags = (unsigned int*)d_ws;
    float* partials = (float*)((char*)d_ws + 64);

    hipMemsetAsync(d_ws, 0, 64, stream);
    detect_kernel<<<(NCELL/4 + 255)/256, 256, 0, stream>>>((const unsigned int*)om, flags);
    out_kernel<<<B_*A_*G_, 256, 0, stream>>>(x, out);
    loss_kernel<<<NCELL/256, 256, 0, stream>>>(x, iou, om, nm, tw, th, tcls, tconf, tbox,
                                               flags, partials);
    final_kernel<<<1, 256, 0, stream>>>(partials, out + OUTN);
}

// Round 2
// 85.625 us; speedup vs baseline: 1.5070x; 1.5070x over previous
//
#include <hip/hip_runtime.h>

#define B_ 16
#define A_ 3
#define G_ 76
#define GG_ (G_*G_)             // 5776
#define NC_ 80
#define C_ 85
#define NCELL (B_*A_*GG_)       // 277248
#define NBLK (B_*A_*G_)         // 3648
#define OUTN ((size_t)NCELL*C_) // 23566080

__device__ __forceinline__ float sigf(float v){ return 1.0f/(1.0f + __expf(-v)); }
__device__ __forceinline__ float clog_(float p){ return fmaxf(__logf(p), -100.0f); }
__device__ __forceinline__ float bcef(float p, float t){ return -(t*clog_(p) + (1.0f-t)*clog_(1.0f-p)); }

// ---------------- mask dtype detection ----------------
__global__ __launch_bounds__(256) void detect_kernel(const unsigned int* __restrict__ m,
                                                     unsigned int* __restrict__ flags){
    unsigned idx = blockIdx.x*256u + threadIdx.x;
    unsigned v = (idx < (NCELL/4)) ? m[idx] : 0u;
    int n01 = (v > 1u);
    int nfl = (v != 0u) && (v != 0x3F800000u);
    if (__any(n01) && (threadIdx.x & 63) == 0) atomicOr(&flags[0], 1u);
    if (__any(nfl) && (threadIdx.x & 63) == 0) atomicOr(&flags[1], 1u);
}

// ---------------- fused transpose+transform+loss ----------------
// block = (ba, i): 85x76 tile. float4 loads, transposed LDS, float4 stores,
// then row loss from LDS.
__global__ __launch_bounds__(256) void fused_kernel(
        const float* __restrict__ x, const float* __restrict__ iou,
        const void* __restrict__ om, const void* __restrict__ nm,
        const float* __restrict__ tw, const float* __restrict__ th,
        const float* __restrict__ tcls, const float* __restrict__ tconf,
        const float* __restrict__ tbox, const unsigned int* __restrict__ flags,
        float* __restrict__ out, float* __restrict__ partials){
    __shared__ __align__(16) float ot[G_*C_];   // [m][k] transposed tile (output layout)
    __shared__ float raww[2][G_];               // raw pw, ph per cell
    int blk = blockIdx.x;
    int i  = blk % G_;
    int ba = blk / G_;
    int a  = ba % A_;
    float aw8 = (a==0)?12.0f:((a==1)?19.0f:40.0f);   // anchor_w/stride*stride = anchor_w
    float ah8 = (a==0)?16.0f:((a==1)?36.0f:28.0f);
    const float* base = x + ((size_t)ba*C_)*GG_ + i*G_;

    // Phase 1: load 85 rows x 19 float4, transform, transpose into LDS
    for (int idx = threadIdx.x; idx < C_*19; idx += 256){
        int k  = idx / 19;
        int j4 = idx - k*19;
        float4 v = *(const float4*)(base + (size_t)k*GG_ + j4*4);
        int m0 = j4*4;
        float e0=v.x, e1=v.y, e2=v.z, e3=v.w;
        float r0,r1,r2,r3;
        if (k >= 4){
            r0=sigf(e0); r1=sigf(e1); r2=sigf(e2); r3=sigf(e3);
        } else if (k == 0){
            r0=(sigf(e0)+(float)(m0+0))*8.0f; r1=(sigf(e1)+(float)(m0+1))*8.0f;
            r2=(sigf(e2)+(float)(m0+2))*8.0f; r3=(sigf(e3)+(float)(m0+3))*8.0f;
        } else if (k == 1){
            float fi = (float)i;
            r0=(sigf(e0)+fi)*8.0f; r1=(sigf(e1)+fi)*8.0f;
            r2=(sigf(e2)+fi)*8.0f; r3=(sigf(e3)+fi)*8.0f;
        } else if (k == 2){
            r0=__expf(e0)*aw8; r1=__expf(e1)*aw8; r2=__expf(e2)*aw8; r3=__expf(e3)*aw8;
            raww[0][m0+0]=e0; raww[0][m0+1]=e1; raww[0][m0+2]=e2; raww[0][m0+3]=e3;
        } else {
            r0=__expf(e0)*ah8; r1=__expf(e1)*ah8; r2=__expf(e2)*ah8; r3=__expf(e3)*ah8;
            raww[1][m0+0]=e0; raww[1][m0+1]=e1; raww[1][m0+2]=e2; raww[1][m0+3]=e3;
        }
        ot[(m0+0)*C_ + k] = r0;
        ot[(m0+1)*C_ + k] = r1;
        ot[(m0+2)*C_ + k] = r2;
        ot[(m0+3)*C_ + k] = r3;
    }
    __syncthreads();

    // Phase 2: linear float4 copy-out (coalesced)
    {
        float4* dst4 = (float4*)(out + (size_t)blk*(G_*C_));
        const float4* src4 = (const float4*)ot;
        for (int idx = threadIdx.x; idx < (G_*C_)/4; idx += 256)
            dst4[idx] = src4[idx];
    }

    // Phase 3: loss for this row's 76 cells
    float s0=0.f, s1=0.f, s2=0.f, s3=0.f, s4=0.f, s5=0.f;
    if (threadIdx.x < G_){
        int j = threadIdx.x;
        size_t n = (size_t)ba*GG_ + (size_t)i*G_ + j;
        int mode = (flags[0]==0u) ? 0 : ((flags[1]==0u) ? 1 : 2);
        bool obj, noobj;
        if (mode == 0){
            obj   = ((const int*)om)[n] != 0;
            noobj = ((const int*)nm)[n] != 0;
        } else if (mode == 1){
            obj   = ((const float*)om)[n] != 0.0f;
            noobj = ((const float*)nm)[n] != 0.0f;
        } else {
            obj   = ((const unsigned char*)om)[n] != 0;
            noobj = ((const unsigned char*)nm)[n] != 0;
        }
        if (obj || noobj){
            float pconf = ot[j*C_ + 4];
            float bc = bcef(pconf, tconf[n]);
            if (noobj){ s2 = bc; s5 = 1.f; }
            if (obj){
                s1 = bc; s4 = 1.f;
                float bx = ot[j*C_+0]*0.125f;
                float by = ot[j*C_+1]*0.125f;
                float bw = ot[j*C_+2]*0.125f;
                float bh = ot[j*C_+3]*0.125f;
                float pwv = raww[0][j], phv = raww[1][j];
                float4 tb = *(const float4*)(tbox + n*4);
                float txc=tb.x, tyc=tb.y, twd=tb.z, tht=tb.w;
                float tx1 = txc - twd*0.5f, ty1 = tyc - tht*0.5f;
                float tx2 = txc + twd*0.5f, ty2 = tyc + tht*0.5f;
                float px1 = bx - bw*0.5f,  py1 = by - bh*0.5f;
                float px2 = bx + bw*0.5f,  py2 = by + bh*0.5f;
                float xc1 = fminf(px1, tx1), yc1 = fminf(py1, ty1);
                float xc2 = fmaxf(px2, tx2), yc2 = fmaxf(py2, ty2);
                float cc = (xc2-xc1)*(xc2-xc1) + (yc2-yc1)*(yc2-yc1) + 1e-7f;
                float dd = (txc-bx)*(txc-bx) + (tyc-by)*(tyc-by);
                float rdiou = dd/cc;
                float dat = atanf(tw[n]/th[n]) - atanf(pwv/phv);
                float vv = 0.40528473456935108577f * dat*dat;
                float Si = 1.0f - iou[n];
                float alpha = vv/(Si+vv);
                s0 = 1.0f - iou[n] + rdiou + alpha*vv;
                const float* tcl = tcls + n*NC_;
                float cls = 0.f;
                #pragma unroll 4
                for (int c=0;c<NC_;c++)
                    cls += bcef(ot[j*C_+5+c], tcl[c]);
                s3 = cls;
            }
        }
    }
    // block reduction (deterministic)
    float vals[6] = {s0, s1, s2, s3, s4, s5};
    #pragma unroll
    for (int q=0;q<6;q++){
        float v = vals[q];
        for (int o=32;o>0;o>>=1) v += __shfl_down(v, o, 64);
        vals[q] = v;
    }
    __shared__ float sm[6][4];
    int lane = threadIdx.x & 63, wid = threadIdx.x >> 6;
    if (lane == 0){
        #pragma unroll
        for (int q=0;q<6;q++) sm[q][wid] = vals[q];
    }
    __syncthreads();
    if (threadIdx.x == 0){
        #pragma unroll
        for (int q=0;q<6;q++)
            partials[(size_t)blk*6+q] = sm[q][0]+sm[q][1]+sm[q][2]+sm[q][3];
    }
}

// ---------------- final reduction ----------------
__global__ __launch_bounds__(256) void final_kernel(const float* __restrict__ partials,
                                                    float* __restrict__ out_loss){
    double acc[6] = {0,0,0,0,0,0};
    for (int idx = threadIdx.x; idx < NBLK; idx += 256){
        #pragma unroll
        for (int q=0;q<6;q++) acc[q] += (double)partials[(size_t)idx*6+q];
    }
    #pragma unroll
    for (int q=0;q<6;q++){
        double v = acc[q];
        for (int o=32;o>0;o>>=1) v += __shfl_down(v, o, 64);
        acc[q] = v;
    }
    __shared__ double sm[6][4];
    int lane = threadIdx.x & 63, wid = threadIdx.x >> 6;
    if (lane == 0){
        #pragma unroll
        for (int q=0;q<6;q++) sm[q][wid] = acc[q];
    }
    __syncthreads();
    if (threadIdx.x == 0){
        double s[6];
        #pragma unroll
        for (int q=0;q<6;q++) s[q] = sm[q][0]+sm[q][1]+sm[q][2]+sm[q][3];
        double cnt_o = fmax(s[4], 1.0);
        double cnt_n = fmax(s[5], 1.0);
        double total = s[0]/(double)B_
                     + s[1]/cnt_o
                     + 100.0*s[2]/cnt_n
                     + s[3]/(cnt_o*(double)NC_);
        *out_loss = (float)total;
    }
}

extern "C" void kernel_launch(void* const* d_in, const int* in_sizes, int n_in,
                              void* d_out, int out_size, void* d_ws, size_t ws_size,
                              hipStream_t stream){
    const float* x     = (const float*)d_in[0];
    const float* iou   = (const float*)d_in[1];
    const void*  om    = d_in[2];
    const void*  nm    = d_in[3];
    const float* tw    = (const float*)d_in[4];
    const float* th    = (const float*)d_in[5];
    const float* tcls  = (const float*)d_in[6];
    const float* tconf = (const float*)d_in[7];
    const float* tbox  = (const float*)d_in[8];
    float* out = (float*)d_out;

    unsigned int* flags = (unsigned int*)d_ws;
    float* partials = (float*)((char*)d_ws + 64);

    hipMemsetAsync(d_ws, 0, 64, stream);
    detect_kernel<<<(NCELL/4 + 255)/256, 256, 0, stream>>>((const unsigned int*)om, flags);
    fused_kernel<<<NBLK, 256, 0, stream>>>(x, iou, om, nm, tw, th, tcls, tconf, tbox,
                                           flags, out, partials);
    final_kernel<<<1, 256, 0, stream>>>(partials, out + OUTN);
}